// Round 8
// baseline (253.979 us; speedup 1.0000x reference)
//
#include <hip/hip_runtime.h>
#include <math.h>

#define CH  256
#define SPA 4096
#define BB  16
#define PLANE 16777216   // 16*256*4096 elements per tensor

typedef _Float16 f16x8 __attribute__((ext_vector_type(8)));
typedef _Float16 f16x4 __attribute__((ext_vector_type(4)));
typedef float    f32x4 __attribute__((ext_vector_type(4)));

__device__ __forceinline__ void gload16(const void* g, void* l) {
    __builtin_amdgcn_global_load_lds(
        (const __attribute__((address_space(1))) unsigned int*)g,
        (__attribute__((address_space(3))) unsigned int*)l, 16, 0, 0);
}

// ---------- channel transpose fp16: src[b][c][s] -> dst[b][s][c] ----------
__global__ __launch_bounds__(256) void cpose_kernel(
    const _Float16* __restrict__ src, _Float16* __restrict__ dst)
{
    __shared__ _Float16 T[64][68];
    const int t  = threadIdx.x;
    const int b  = blockIdx.x >> 8;
    const int st = (blockIdx.x >> 2) & 63;
    const int ct = blockIdx.x & 3;
    const int s0 = st << 6, c0 = ct << 6;

    #pragma unroll
    for (int p = 0; p < 4; ++p) {
        int fi = (p << 8) + t;
        int r = fi >> 4, s4 = (fi & 15) << 2;
        f16x4 v = *(const f16x4*)(src + (((size_t)((b << 8) + c0 + r)) << 12) + s0 + s4);
        *(f16x4*)&T[r][s4] = v;
    }
    __syncthreads();

    const int s  = t >> 2;
    const int cg = (t & 3) << 4;
    f16x8 h0, h1;
    #pragma unroll
    for (int i = 0; i < 16; ++i) {
        _Float16 hv = T[cg + i][s];
        if (i < 8) h0[i] = hv; else h1[i - 8] = hv;
    }
    const size_t obase = (((size_t)((b << 12) + s0 + s)) << 8) + c0 + cg;
    *(f16x8*)(dst + obase)     = h0;
    *(f16x8*)(dst + obase + 8) = h1;
}

// ---------- weight cvt: 4 matrices [o][k] f32 -> fp16 ----------
__global__ __launch_bounds__(256) void wcvt_kernel(
    const float* __restrict__ w0, const float* __restrict__ w1,
    const float* __restrict__ w2, const float* __restrict__ w3,
    _Float16* __restrict__ dst)
{
    const int idx = blockIdx.x * 256 + threadIdx.x;
    dst[idx]             = (_Float16)w0[idx];
    dst[65536 + idx]     = (_Float16)w1[idx];
    dst[131072 + idx]    = (_Float16)w2[idx];
    dst[196608 + idx]    = (_Float16)w3[idx];
}

// ---------- fused f/g/h conv, v8: xpose FUSED (reads raw f32 x) ----------
// Deletes the xpose kernel + xT HBM round trip. Per K-step: stage the f32
// tile x[b][kb+32c][s0+64s] (8 KB) via coalesced global_load_lds (rows are
// s-contiguous, linear dest). A-fragments are built by per-lane COLUMN reads
// of the f32 tile (8 x ds_read_b32, stride 256 B -> bank = s%32, ~free) +
// in-register f32->f16 cvt (same rounding as xpose did => identical numerics).
// K-loop sync structure byte-identical to v7 (counted vmcnt, now 5 loads);
// B path, coalesced epilogue unchanged.
__global__ __launch_bounds__(256, 4) void gemm_fgh_kernel(
    const float* __restrict__ x, const _Float16* __restrict__ wc,
    const float* __restrict__ bias0, const float* __restrict__ bias1,
    const float* __restrict__ bias2, _Float16* __restrict__ outp)
{
    __shared__ char SS[2][20480];   // per buf: X 32x64 f32 (8 KB) + 3x B 64x32 f16 (12 KB)

    const int tid = threadIdx.x;
    const int w = tid >> 6, lane = tid & 63, q = lane >> 4, li = lane & 15;
    const int wx = w & 1, wy = w >> 1;      // wave owns 32s x 32o

    // XCD-aware remap (4096 blocks = 8 XCDs x 512)
    const int r_ = ((blockIdx.x & 7) << 9) + (blockIdx.x >> 3);
    const int ot    = r_ & 3;               // 4 o-tiles of 64
    const int stile = (r_ >> 2) & 63;       // 64 s-tiles of 64
    const int b     = r_ >> 8;              // 16 batches
    const int s0 = stile << 6, o0 = ot << 6;

    const float* biases[3] = {bias0, bias1, bias2};

    f32x4 acc[3][2][2];                     // [matrix][s-frag][o-frag]
    #pragma unroll
    for (int m = 0; m < 3; ++m)
        #pragma unroll
        for (int t2 = 0; t2 < 2; ++t2)
            #pragma unroll
            for (int u = 0; u < 2; ++u) acc[m][t2][u] = (f32x4){0.f, 0.f, 0.f, 0.f};

    const int rr = tid >> 2;                              // B staged row 0..63
    const int cs = (((tid & 3) ^ ((rr >> 1) & 3)) << 3);  // B pre-swizzled k-chunk
    const int sw = (li >> 1) & 3;                         // B read-side chunk XOR

    auto STAGE = [&](char* buf, int kb) {                 // 5 gload16 per thread
        float* xf = (float*)buf;
        _Float16* sB = (_Float16*)(buf + 8192);
        // X f32 tile [32c][64s]: chunk k=tid -> (c=k>>4, s=(k&15)*4); 2nd half +16c
        const size_t gx1 = (((size_t)((b << 8) + kb + (tid >> 4))) << 12)
                           + s0 + ((tid & 15) << 2);
        gload16(x + gx1, xf + tid * 4);
        gload16(x + gx1 + (16ull << 12), xf + 1024 + tid * 4);
        #pragma unroll
        for (int m = 0; m < 3; ++m) {
            const size_t gb = (((size_t)(o0 + rr)) << 8) + m * 65536 + kb + cs;
            gload16(wc + gb, sB + m * 2048 + tid * 8);
        }
    };

    auto COMPUTE = [&](const char* buf) {
        const float* xf = (const float*)buf;
        const _Float16* sBb = (const _Float16*)(buf + 8192);
        f16x8 a[2];
        #pragma unroll
        for (int t2 = 0; t2 < 2; ++t2) {
            const int r = (wy << 5) + (t2 << 4) + li;
            #pragma unroll
            for (int j = 0; j < 8; ++j)                  // column read + cvt
                a[t2][j] = (_Float16)xf[(((q << 3) + j) << 6) + r];
        }
        #pragma unroll
        for (int m = 0; m < 3; ++m) {
            const _Float16* sB = sBb + m * 2048;
            f16x8 b0 = *(const f16x8*)(sB + (((wx << 5) + li) * 32) + ((q ^ sw) << 3));
            f16x8 b1 = *(const f16x8*)(sB + (((wx << 5) + 16 + li) * 32) + ((q ^ sw) << 3));
            #pragma unroll
            for (int t2 = 0; t2 < 2; ++t2) {
                acc[m][t2][0] = __builtin_amdgcn_mfma_f32_16x16x32_f16(a[t2], b0, acc[m][t2][0], 0, 0, 0);
                acc[m][t2][1] = __builtin_amdgcn_mfma_f32_16x16x32_f16(a[t2], b1, acc[m][t2][1], 0, 0, 0);
            }
        }
    };

    // prologue: stage tile 0 (no wait — first wait is in iter 0)
    STAGE(SS[0], 0);

    #pragma unroll 1
    for (int ks = 0; ks < 7; ++ks) {
        STAGE(SS[(ks + 1) & 1], (ks + 1) << 5);          // tile k+1 in flight
        asm volatile("s_waitcnt vmcnt(5)" ::: "memory"); // tile k's 5 loads done
        __builtin_amdgcn_s_barrier();                    // all waves' tile k landed
        COMPUTE(SS[ks & 1]);
        asm volatile("s_waitcnt lgkmcnt(0)" ::: "memory"); // my LDS reads retired
        __builtin_amdgcn_s_barrier();                    // WAR: next STAGE overwrites
    }
    asm volatile("s_waitcnt vmcnt(0)" ::: "memory");     // drain tile 7
    __builtin_amdgcn_s_barrier();
    COMPUTE(SS[1]);

    // ---- epilogue: LDS-repacked fully-coalesced stores (pitch 72) ----
    _Float16* Lr = (_Float16*)&SS[0][0];   // 64 rows x pitch 72 halves = 9216 B
    #pragma unroll
    for (int m = 0; m < 3; ++m) {
        __syncthreads();                // prior LDS reads done before overwrite
        #pragma unroll
        for (int u = 0; u < 2; ++u) {
            const int o = (wx << 5) + (u << 4) + li;
            const float bz = biases[m][o0 + o];
            #pragma unroll
            for (int t2 = 0; t2 < 2; ++t2) {
                const int s = (wy << 5) + (t2 << 4) + (q << 2);
                f32x4 v = acc[m][t2][u];
                f16x4 pv;
                pv[0] = (_Float16)(v[0] + bz); pv[1] = (_Float16)(v[1] + bz);
                pv[2] = (_Float16)(v[2] + bz); pv[3] = (_Float16)(v[3] + bz);
                *(f16x4*)&Lr[o * 72 + s] = pv;
            }
        }
        __syncthreads();                // ds_writes visible to all waves
        _Float16* ob = outp + (size_t)m * PLANE;
        #pragma unroll
        for (int it = 0; it < 2; ++it) {
            const int idx = (it << 8) + tid;
            const int row = idx >> 3, c8 = (idx & 7) << 3;
            f16x8 hv = *(const f16x8*)&Lr[row * 72 + c8];
            *(f16x8*)(ob + (((size_t)((b << 8) + o0 + row)) << 12) + s0 + c8) = hv;
        }
    }
}

// ---------- final conv (single matrix, f32 out), 128s x 128o ----------
// v7: counted-vmcnt K-loop + lgkmcnt(0) WAR drain + coalesced f32 epilogue.
__global__ __launch_bounds__(256) void gemm16_kernel(
    const _Float16* __restrict__ xT, const _Float16* __restrict__ wp,
    const float* __restrict__ bias, float* __restrict__ outp)
{
    __shared__ _Float16 S[2][8192];    // per buf: A 128x32 + B 128x32

    const int tid = threadIdx.x;
    const int w = tid >> 6, lane = tid & 63, quad = lane >> 4, li = lane & 15;
    const int wx = w & 1, wy = w >> 1;

    // XCD-aware remap (1024 blocks = 8 XCDs x 128)
    const int r_ = ((blockIdx.x & 7) << 7) + (blockIdx.x >> 3);
    const int ot    = r_ & 1;
    const int stile = (r_ >> 1) & 31;
    const int b     = r_ >> 6;
    const int s0 = stile << 7, o0 = ot << 7;

    f32x4 acc[4][4];
    #pragma unroll
    for (int t2 = 0; t2 < 4; ++t2)
        #pragma unroll
        for (int u = 0; u < 4; ++u) acc[t2][u] = (f32x4){0.f, 0.f, 0.f, 0.f};

    const int rr = lane >> 2;
    const int cs = (((lane & 3) ^ ((rr >> 1) & 3)) << 3);  // pre-swizzled source chunk
    const int sw = (li >> 1) & 3;

    auto STAGE = [&](_Float16* sAB, int kb) {              // 4 gload_lds per wave
        #pragma unroll
        for (int j = 0; j < 32; j += 16) {
            const int r = (w << 5) + j + rr;
            const size_t ga = (((size_t)((b << 12) + s0 + r)) << 8) + kb + cs;
            const size_t gb = ((size_t)(o0 + r) << 8) + kb + cs;
            const int lo_ = ((w << 5) + j) * 32 + lane * 8;
            gload16(xT + ga, sAB + lo_);
            gload16(wp + gb, sAB + 4096 + lo_);
        }
    };

    auto COMPUTE = [&](const _Float16* sAB) {
        f16x8 a[4], bfr[4];
        #pragma unroll
        for (int t2 = 0; t2 < 4; ++t2) {
            a[t2]   = *(const f16x8*)(sAB + ((wy << 6) + (t2 << 4) + li) * 32 + ((quad ^ sw) << 3));
            bfr[t2] = *(const f16x8*)(sAB + 4096 + ((wx << 6) + (t2 << 4) + li) * 32 + ((quad ^ sw) << 3));
        }
        #pragma unroll
        for (int t2 = 0; t2 < 4; ++t2)
            #pragma unroll
            for (int u = 0; u < 4; ++u)
                acc[t2][u] = __builtin_amdgcn_mfma_f32_16x16x32_f16(a[t2], bfr[u], acc[t2][u], 0, 0, 0);
    };

    STAGE(S[0], 0);

    #pragma unroll 1
    for (int ks = 0; ks < 7; ++ks) {
        STAGE(S[(ks + 1) & 1], (ks + 1) << 5);
        asm volatile("s_waitcnt vmcnt(4)" ::: "memory");
        __builtin_amdgcn_s_barrier();
        COMPUTE(S[ks & 1]);
        asm volatile("s_waitcnt lgkmcnt(0)" ::: "memory");
        __builtin_amdgcn_s_barrier();
    }
    asm volatile("s_waitcnt vmcnt(0)" ::: "memory");
    __builtin_amdgcn_s_barrier();
    COMPUTE(S[1]);

    // ---- epilogue: per-o-half LDS repack, coalesced float4 streams ----
    float* Lf = (float*)&S[0][0];       // 64 rows x 128 f32 = 32 KB, XOR-swizzled
    #pragma unroll
    for (int h = 0; h < 2; ++h) {
        __syncthreads();
        if (wx == h) {
            #pragma unroll
            for (int u = 0; u < 4; ++u) {
                const int r = (u << 4) + li;
                const float bz = bias[o0 + (h << 6) + r];
                #pragma unroll
                for (int t2 = 0; t2 < 4; ++t2) {
                    const int s = (wy << 6) + (t2 << 4) + (quad << 2);
                    f32x4 v = acc[t2][u];
                    f32x4 pv = {v[0] + bz, v[1] + bz, v[2] + bz, v[3] + bz};
                    *(f32x4*)&Lf[r * 128 + (s ^ ((r & 7) << 2))] = pv;
                }
            }
        }
        __syncthreads();
        #pragma unroll
        for (int it = 0; it < 8; ++it) {
            const int idx = (it << 8) + tid;
            const int row = idx >> 5, c4 = (idx & 31) << 2;
            f32x4 v = *(const f32x4*)&Lf[row * 128 + (c4 ^ ((row & 7) << 2))];
            float4 pv = {v[0], v[1], v[2], v[3]};
            *(float4*)(outp + (((size_t)((b << 8) + o0 + (h << 6) + row)) << 12) + s0 + c4) = pv;
        }
    }
}

// ---------- MFMA attention: one block per (b,c) ----------
__global__ __launch_bounds__(256) void attn_mfma_kernel(
    const _Float16* __restrict__ fx, const _Float16* __restrict__ gx,
    const _Float16* __restrict__ hx, _Float16* __restrict__ ob)
{
    __shared__ _Float16 L[23040];           // 46080 B
    const int FT = 0, GT = 4608, HM = 9216; // pitch-72 64-row panels
    const int FR = 13824, GR = 18432;       // raw staging
    const int PT = 13824;                   // P^T aliases FR

    const int t = threadIdx.x;
    const int wave = t >> 6, lane = t & 63, q = lane >> 4, li = lane & 15;
    const int bc = blockIdx.x;
    const _Float16* Fp = fx + (size_t)bc * SPA;
    const _Float16* Gp = gx + (size_t)bc * SPA;
    const _Float16* Hp = hx + (size_t)bc * SPA;
    _Float16* Op = ob + (size_t)bc * SPA;

    #pragma unroll
    for (int p = 0; p < 2; ++p) {
        int ci = t + (p << 8);
        int h = ci >> 3, w8 = (ci & 7) << 3;
        *(f16x8*)&L[FR + h * 72 + w8] = *(const f16x8*)(Fp + h * 64 + w8);
        *(f16x8*)&L[GR + h * 72 + w8] = *(const f16x8*)(Gp + h * 64 + w8);
        *(f16x8*)&L[HM + h * 72 + w8] = *(const f16x8*)(Hp + h * 64 + w8);
    }
    __syncthreads();

    // transpose F,G via MFMA x identity
    {
        const int src = (wave < 2) ? FR : GR;
        const int dst = (wave < 2) ? FT : GT;
        const int mtb = (wave & 1) << 1;
        f16x8 id0, id1;
        #pragma unroll
        for (int j = 0; j < 8; ++j) {
            id0[j] = (_Float16)(((q << 3) + j == li)      ? 1.0f : 0.0f);
            id1[j] = (_Float16)(((q << 3) + j == li + 16) ? 1.0f : 0.0f);
        }
        #pragma unroll
        for (int mi = 0; mi < 2; ++mi) {
            const int mt = mtb + mi;
            f16x8 a0 = *(const f16x8*)&L[src + (mt * 16 + li) * 72 + (q << 3)];
            f16x8 a1 = *(const f16x8*)&L[src + (mt * 16 + li) * 72 + 32 + (q << 3)];
            #pragma unroll
            for (int nt = 0; nt < 4; ++nt) {
                f32x4 d = {0.f, 0.f, 0.f, 0.f};
                d = __builtin_amdgcn_mfma_f32_16x16x32_f16(
                        (nt < 2) ? a0 : a1, (nt & 1) ? id1 : id0, d, 0, 0, 0);
                f16x4 e;
                e[0] = (_Float16)d[0]; e[1] = (_Float16)d[1];
                e[2] = (_Float16)d[2]; e[3] = (_Float16)d[3];
                *(f16x4*)&L[dst + (nt * 16 + li) * 72 + mt * 16 + (q << 2)] = e;
            }
        }
    }
    __syncthreads();

    // S-GEMM + register softmax
    {
        f16x8 a0 = *(const f16x8*)&L[FT + (wave * 16 + li) * 72 + (q << 3)];
        f16x8 a1 = *(const f16x8*)&L[FT + (wave * 16 + li) * 72 + 32 + (q << 3)];
        f32x4 s_[4];
        #pragma unroll
        for (int nt = 0; nt < 4; ++nt) {
            f16x8 b0 = *(const f16x8*)&L[GT + (nt * 16 + li) * 72 + (q << 3)];
            f16x8 b1 = *(const f16x8*)&L[GT + (nt * 16 + li) * 72 + 32 + (q << 3)];
            f32x4 acc = {0.f, 0.f, 0.f, 0.f};
            acc = __builtin_amdgcn_mfma_f32_16x16x32_f16(a0, b0, acc, 0, 0, 0);
            acc = __builtin_amdgcn_mfma_f32_16x16x32_f16(a1, b1, acc, 0, 0, 0);
            s_[nt] = acc;
        }
        float mx[4], sm[4];
        #pragma unroll
        for (int r = 0; r < 4; ++r) {
            float m0 = fmaxf(fmaxf(s_[0][r], s_[1][r]), fmaxf(s_[2][r], s_[3][r]));
            m0 = fmaxf(m0, __shfl_xor(m0, 1));
            m0 = fmaxf(m0, __shfl_xor(m0, 2));
            m0 = fmaxf(m0, __shfl_xor(m0, 4));
            m0 = fmaxf(m0, __shfl_xor(m0, 8));
            mx[r] = m0;
        }
        #pragma unroll
        for (int nt = 0; nt < 4; ++nt)
            #pragma unroll
            for (int r = 0; r < 4; ++r)
                s_[nt][r] = __expf(s_[nt][r] - mx[r]);
        #pragma unroll
        for (int r = 0; r < 4; ++r) {
            float s0 = (s_[0][r] + s_[1][r]) + (s_[2][r] + s_[3][r]);
            s0 += __shfl_xor(s0, 1);
            s0 += __shfl_xor(s0, 2);
            s0 += __shfl_xor(s0, 4);
            s0 += __shfl_xor(s0, 8);
            sm[r] = 1.f / s0;
        }
        #pragma unroll
        for (int nt = 0; nt < 4; ++nt) {
            const int v  = nt * 16 + li;
            const int sw = ((v >> 3) & 7) << 3;
            #pragma unroll
            for (int r = 0; r < 4; ++r) {
                const int w = wave * 16 + (q << 2) + r;
                L[PT + v * 72 + (w ^ sw)] = (_Float16)(s_[nt][r] * sm[r]);
            }
        }
    }
    __syncthreads();

    // O-GEMM
    {
        f16x8 a0 = *(const f16x8*)&L[HM + (wave * 16 + li) * 72 + (q << 3)];
        f16x8 a1 = *(const f16x8*)&L[HM + (wave * 16 + li) * 72 + 32 + (q << 3)];
        #pragma unroll
        for (int nt = 0; nt < 4; ++nt) {
            const int v  = nt * 16 + li;
            const int sw = ((v >> 3) & 7) << 3;
            f16x8 b0 = *(const f16x8*)&L[PT + v * 72 + ((q << 3) ^ sw)];
            f16x8 b1 = *(const f16x8*)&L[PT + v * 72 + ((32 + (q << 3)) ^ sw)];
            f32x4 acc = {0.f, 0.f, 0.f, 0.f};
            acc = __builtin_amdgcn_mfma_f32_16x16x32_f16(a0, b0, acc, 0, 0, 0);
            acc = __builtin_amdgcn_mfma_f32_16x16x32_f16(a1, b1, acc, 0, 0, 0);
            #pragma unroll
            for (int r = 0; r < 4; ++r)
                Op[(wave * 16 + (q << 2) + r) * 64 + v] = (_Float16)acc[r];
        }
    }
}

extern "C" void kernel_launch(void* const* d_in, const int* in_sizes, int n_in,
                              void* d_out, int out_size, void* d_ws, size_t ws_size,
                              hipStream_t stream)
{
    const float* x  = (const float*)d_in[0];
    const float* wf = (const float*)d_in[1];
    const float* bf = (const float*)d_in[2];
    const float* wg = (const float*)d_in[3];
    const float* bg = (const float*)d_in[4];
    const float* wh = (const float*)d_in[5];
    const float* bh = (const float*)d_in[6];
    const float* wv = (const float*)d_in[7];
    const float* bv = (const float*)d_in[8];

    char* base = (char*)d_ws;
    const size_t MB = 1ull << 20;
    _Float16* fxb = (_Float16*)(base + 32 * MB);   // [32,64) (f), g [64,96), h [96,128)
    _Float16* ob  = (_Float16*)(base + 128 * MB);  // [128,160)
    _Float16* obT = (_Float16*)base;               // [0,32)
    _Float16* wc  = (_Float16*)(base + 160 * MB);  // 512 KB

    _Float16* gxb = fxb + PLANE;
    _Float16* hxb = gxb + PLANE;

    dim3 blk(256);
    wcvt_kernel<<<256, blk, 0, stream>>>(wf, wg, wh, wv, wc);

    gemm_fgh_kernel<<<4096, blk, 0, stream>>>(x, wc, bf, bg, bh, fxb);

    attn_mfma_kernel<<<4096, blk, 0, stream>>>(fxb, gxb, hxb, ob);

    cpose_kernel<<<4096, blk, 0, stream>>>(ob, obT);

    gemm16_kernel<<<1024, blk, 0, stream>>>(obT, wc + 196608, bv, (float*)d_out);
}

// Round 9
// 245.196 us; speedup vs baseline: 1.0358x; 1.0358x over previous
//
#include <hip/hip_runtime.h>
#include <math.h>

#define CH  256
#define SPA 4096
#define BB  16
#define PLANE 16777216   // 16*256*4096 elements per tensor

typedef _Float16 f16x8 __attribute__((ext_vector_type(8)));
typedef _Float16 f16x4 __attribute__((ext_vector_type(4)));
typedef float    f32x4 __attribute__((ext_vector_type(4)));

__device__ __forceinline__ void gload16(const void* g, void* l) {
    __builtin_amdgcn_global_load_lds(
        (const __attribute__((address_space(1))) unsigned int*)g,
        (__attribute__((address_space(3))) unsigned int*)l, 16, 0, 0);
}

// ---------- x transpose + fp16 cvt: src[b][r][s] f32 -> dst[b][s][r] fp16 ----------
__global__ __launch_bounds__(256) void xpose_kernel(
    const float* __restrict__ src, _Float16* __restrict__ dst)
{
    __shared__ float T[64][65];
    const int t  = threadIdx.x;
    const int b  = blockIdx.x >> 8;
    const int st = (blockIdx.x >> 2) & 63;
    const int rt = blockIdx.x & 3;
    const int s0 = st << 6, r0 = rt << 6;

    #pragma unroll
    for (int p = 0; p < 4; ++p) {
        int k = (t >> 4) + (p << 4);
        float4 v = *(const float4*)(src + (((size_t)((b << 8) + r0 + k)) << 12)
                                        + s0 + ((t & 15) << 2));
        T[k][((t & 15) << 2) + 0] = v.x;
        T[k][((t & 15) << 2) + 1] = v.y;
        T[k][((t & 15) << 2) + 2] = v.z;
        T[k][((t & 15) << 2) + 3] = v.w;
    }
    __syncthreads();

    const int s  = t >> 2;
    const int kg = (t & 3) << 4;
    const size_t obase = (((size_t)((b << 12) + s0 + s)) << 8) + r0 + kg;

    f16x8 h0, h1;
    #pragma unroll
    for (int i = 0; i < 16; ++i) {
        _Float16 hv = (_Float16)T[kg + i][s];
        if (i < 8) h0[i] = hv; else h1[i - 8] = hv;
    }
    *(f16x8*)(dst + obase)     = h0;
    *(f16x8*)(dst + obase + 8) = h1;
}

// ---------- channel transpose fp16: src[b][c][s] -> dst[b][s][c] ----------
__global__ __launch_bounds__(256) void cpose_kernel(
    const _Float16* __restrict__ src, _Float16* __restrict__ dst)
{
    __shared__ _Float16 T[64][68];
    const int t  = threadIdx.x;
    const int b  = blockIdx.x >> 8;
    const int st = (blockIdx.x >> 2) & 63;
    const int ct = blockIdx.x & 3;
    const int s0 = st << 6, c0 = ct << 6;

    #pragma unroll
    for (int p = 0; p < 4; ++p) {
        int fi = (p << 8) + t;
        int r = fi >> 4, s4 = (fi & 15) << 2;
        f16x4 v = *(const f16x4*)(src + (((size_t)((b << 8) + c0 + r)) << 12) + s0 + s4);
        *(f16x4*)&T[r][s4] = v;
    }
    __syncthreads();

    const int s  = t >> 2;
    const int cg = (t & 3) << 4;
    f16x8 h0, h1;
    #pragma unroll
    for (int i = 0; i < 16; ++i) {
        _Float16 hv = T[cg + i][s];
        if (i < 8) h0[i] = hv; else h1[i - 8] = hv;
    }
    const size_t obase = (((size_t)((b << 12) + s0 + s)) << 8) + c0 + cg;
    *(f16x8*)(dst + obase)     = h0;
    *(f16x8*)(dst + obase + 8) = h1;
}

// ---------- weight cvt: 4 matrices [o][k] f32 -> fp16 ----------
__global__ __launch_bounds__(256) void wcvt_kernel(
    const float* __restrict__ w0, const float* __restrict__ w1,
    const float* __restrict__ w2, const float* __restrict__ w3,
    _Float16* __restrict__ dst)
{
    const int idx = blockIdx.x * 256 + threadIdx.x;
    dst[idx]             = (_Float16)w0[idx];
    dst[65536 + idx]     = (_Float16)w1[idx];
    dst[131072 + idx]    = (_Float16)w2[idx];
    dst[196608 + idx]    = (_Float16)w3[idx];
}

// ---------- fused f/g/h conv ----------
// v9: v8 fusion REVERTED (xpose restored — in-GEMM f32 column reads cost 5.4M
// bank conflicts + 2x FETCH, 49->86 us). K-loop = v7 (counted vmcnt pipeline,
// lgkmcnt(0) WAR drain). NEW epilogue: all 3 m-planes packed into 3 LDS panels
// (3 x 64x72 halves = 27.6 KB) with ONE barrier pair, then all stores streamed
// back-to-back. v7's per-plane __syncthreads drained vmcnt(0) each time =
// 3 serialized store-latency round trips; this removes 2 of them.
__global__ __launch_bounds__(256, 4) void gemm_fgh_kernel(
    const _Float16* __restrict__ xT, const _Float16* __restrict__ wc,
    const float* __restrict__ bias0, const float* __restrict__ bias1,
    const float* __restrict__ bias2, _Float16* __restrict__ outp)
{
    __shared__ _Float16 S[2][8192];   // per buf: A 64x32 (2048) + 3x B 64x32 (2048)

    const int tid = threadIdx.x;
    const int w = tid >> 6, lane = tid & 63, q = lane >> 4, li = lane & 15;
    const int wx = w & 1, wy = w >> 1;      // wave owns 32s x 32o

    // XCD-aware remap (4096 blocks = 8 XCDs x 512)
    const int r_ = ((blockIdx.x & 7) << 9) + (blockIdx.x >> 3);
    const int ot    = r_ & 3;               // 4 o-tiles of 64
    const int stile = (r_ >> 2) & 63;       // 64 s-tiles of 64
    const int b     = r_ >> 8;              // 16 batches
    const int s0 = stile << 6, o0 = ot << 6;

    const float* biases[3] = {bias0, bias1, bias2};

    f32x4 acc[3][2][2];                     // [matrix][s-frag][o-frag]
    #pragma unroll
    for (int m = 0; m < 3; ++m)
        #pragma unroll
        for (int t2 = 0; t2 < 2; ++t2)
            #pragma unroll
            for (int u = 0; u < 2; ++u) acc[m][t2][u] = (f32x4){0.f, 0.f, 0.f, 0.f};

    const int rr = tid >> 2;                              // staged row 0..63
    const int cs = (((tid & 3) ^ ((rr >> 1) & 3)) << 3);  // pre-swizzled source k-chunk
    const int sw = (li >> 1) & 3;                         // read-side chunk XOR

    auto STAGE = [&](_Float16* sA, int kb) {              // 4 gload_lds per wave
        const size_t ga = (((size_t)((b << 12) + s0 + rr)) << 8) + kb + cs;
        gload16(xT + ga, sA + tid * 8);                   // A 64x32
        #pragma unroll
        for (int m = 0; m < 3; ++m) {
            const size_t gb = (((size_t)(o0 + rr)) << 8) + m * 65536 + kb + cs;
            gload16(wc + gb, sA + 2048 + m * 2048 + tid * 8);
        }
    };

    auto COMPUTE = [&](const _Float16* sA) {
        f16x8 a[2];
        #pragma unroll
        for (int t2 = 0; t2 < 2; ++t2)
            a[t2] = *(const f16x8*)(sA + (((wy << 5) + (t2 << 4) + li) * 32) + ((q ^ sw) << 3));
        #pragma unroll
        for (int m = 0; m < 3; ++m) {
            const _Float16* sB = sA + 2048 + m * 2048;
            f16x8 b0 = *(const f16x8*)(sB + (((wx << 5) + li) * 32) + ((q ^ sw) << 3));
            f16x8 b1 = *(const f16x8*)(sB + (((wx << 5) + 16 + li) * 32) + ((q ^ sw) << 3));
            #pragma unroll
            for (int t2 = 0; t2 < 2; ++t2) {
                acc[m][t2][0] = __builtin_amdgcn_mfma_f32_16x16x32_f16(a[t2], b0, acc[m][t2][0], 0, 0, 0);
                acc[m][t2][1] = __builtin_amdgcn_mfma_f32_16x16x32_f16(a[t2], b1, acc[m][t2][1], 0, 0, 0);
            }
        }
    };

    // prologue: stage tile 0 (no wait — first wait is in iter 0)
    STAGE(S[0], 0);

    #pragma unroll 1
    for (int ks = 0; ks < 7; ++ks) {
        STAGE(S[(ks + 1) & 1], (ks + 1) << 5);           // tile k+1 in flight
        asm volatile("s_waitcnt vmcnt(4)" ::: "memory"); // tile k's 4 loads done
        __builtin_amdgcn_s_barrier();                    // all waves' tile k landed
        COMPUTE(S[ks & 1]);
        asm volatile("s_waitcnt lgkmcnt(0)" ::: "memory"); // my ds_reads retired
        __builtin_amdgcn_s_barrier();                    // WAR: next STAGE overwrites
    }
    asm volatile("s_waitcnt vmcnt(0)" ::: "memory");     // drain tile 7
    __builtin_amdgcn_s_barrier();
    COMPUTE(S[1]);

    // ---- epilogue v9: 3 panels (m*4608 + o*72 + s), single barrier pair ----
    _Float16* Lr = &S[0][0];            // panels span 13824 halves of 16384
    __syncthreads();                    // all waves done reading S[1] (panels overlap)
    #pragma unroll
    for (int m = 0; m < 3; ++m) {
        #pragma unroll
        for (int u = 0; u < 2; ++u) {
            const int o = (wx << 5) + (u << 4) + li;
            const float bz = biases[m][o0 + o];
            #pragma unroll
            for (int t2 = 0; t2 < 2; ++t2) {
                const int s = (wy << 5) + (t2 << 4) + (q << 2);
                f32x4 v = acc[m][t2][u];
                f16x4 pv;
                pv[0] = (_Float16)(v[0] + bz); pv[1] = (_Float16)(v[1] + bz);
                pv[2] = (_Float16)(v[2] + bz); pv[3] = (_Float16)(v[3] + bz);
                *(f16x4*)&Lr[m * 4608 + o * 72 + s] = pv;
            }
        }
    }
    __syncthreads();                    // panels visible to all waves
    #pragma unroll
    for (int m = 0; m < 3; ++m) {       // stores stream back-to-back, no drains
        _Float16* ob = outp + (size_t)m * PLANE;
        #pragma unroll
        for (int it = 0; it < 2; ++it) {
            const int idx = (it << 8) + tid;
            const int row = idx >> 3, c8 = (idx & 7) << 3;
            f16x8 hv = *(const f16x8*)&Lr[m * 4608 + row * 72 + c8];
            *(f16x8*)(ob + (((size_t)((b << 8) + o0 + row)) << 12) + s0 + c8) = hv;
        }
    }
}

// ---------- final conv (single matrix, f32 out), 128s x 128o ----------
// v7: counted-vmcnt K-loop + lgkmcnt(0) WAR drain + coalesced f32 epilogue.
__global__ __launch_bounds__(256) void gemm16_kernel(
    const _Float16* __restrict__ xT, const _Float16* __restrict__ wp,
    const float* __restrict__ bias, float* __restrict__ outp)
{
    __shared__ _Float16 S[2][8192];    // per buf: A 128x32 + B 128x32

    const int tid = threadIdx.x;
    const int w = tid >> 6, lane = tid & 63, quad = lane >> 4, li = lane & 15;
    const int wx = w & 1, wy = w >> 1;

    // XCD-aware remap (1024 blocks = 8 XCDs x 128)
    const int r_ = ((blockIdx.x & 7) << 7) + (blockIdx.x >> 3);
    const int ot    = r_ & 1;
    const int stile = (r_ >> 1) & 31;
    const int b     = r_ >> 6;
    const int s0 = stile << 7, o0 = ot << 7;

    f32x4 acc[4][4];
    #pragma unroll
    for (int t2 = 0; t2 < 4; ++t2)
        #pragma unroll
        for (int u = 0; u < 4; ++u) acc[t2][u] = (f32x4){0.f, 0.f, 0.f, 0.f};

    const int rr = lane >> 2;
    const int cs = (((lane & 3) ^ ((rr >> 1) & 3)) << 3);  // pre-swizzled source chunk
    const int sw = (li >> 1) & 3;

    auto STAGE = [&](_Float16* sAB, int kb) {              // 4 gload_lds per wave
        #pragma unroll
        for (int j = 0; j < 32; j += 16) {
            const int r = (w << 5) + j + rr;
            const size_t ga = (((size_t)((b << 12) + s0 + r)) << 8) + kb + cs;
            const size_t gb = ((size_t)(o0 + r) << 8) + kb + cs;
            const int lo_ = ((w << 5) + j) * 32 + lane * 8;
            gload16(xT + ga, sAB + lo_);
            gload16(wp + gb, sAB + 4096 + lo_);
        }
    };

    auto COMPUTE = [&](const _Float16* sAB) {
        f16x8 a[4], bfr[4];
        #pragma unroll
        for (int t2 = 0; t2 < 4; ++t2) {
            a[t2]   = *(const f16x8*)(sAB + ((wy << 6) + (t2 << 4) + li) * 32 + ((quad ^ sw) << 3));
            bfr[t2] = *(const f16x8*)(sAB + 4096 + ((wx << 6) + (t2 << 4) + li) * 32 + ((quad ^ sw) << 3));
        }
        #pragma unroll
        for (int t2 = 0; t2 < 4; ++t2)
            #pragma unroll
            for (int u = 0; u < 4; ++u)
                acc[t2][u] = __builtin_amdgcn_mfma_f32_16x16x32_f16(a[t2], bfr[u], acc[t2][u], 0, 0, 0);
    };

    STAGE(S[0], 0);

    #pragma unroll 1
    for (int ks = 0; ks < 7; ++ks) {
        STAGE(S[(ks + 1) & 1], (ks + 1) << 5);
        asm volatile("s_waitcnt vmcnt(4)" ::: "memory");
        __builtin_amdgcn_s_barrier();
        COMPUTE(S[ks & 1]);
        asm volatile("s_waitcnt lgkmcnt(0)" ::: "memory");
        __builtin_amdgcn_s_barrier();
    }
    asm volatile("s_waitcnt vmcnt(0)" ::: "memory");
    __builtin_amdgcn_s_barrier();
    COMPUTE(S[1]);

    // ---- epilogue: per-o-half LDS repack, coalesced float4 streams ----
    float* Lf = (float*)&S[0][0];       // 64 rows x 128 f32 = 32 KB, XOR-swizzled
    #pragma unroll
    for (int h = 0; h < 2; ++h) {
        __syncthreads();
        if (wx == h) {
            #pragma unroll
            for (int u = 0; u < 4; ++u) {
                const int r = (u << 4) + li;
                const float bz = bias[o0 + (h << 6) + r];
                #pragma unroll
                for (int t2 = 0; t2 < 4; ++t2) {
                    const int s = (wy << 6) + (t2 << 4) + (quad << 2);
                    f32x4 v = acc[t2][u];
                    f32x4 pv = {v[0] + bz, v[1] + bz, v[2] + bz, v[3] + bz};
                    *(f32x4*)&Lf[r * 128 + (s ^ ((r & 7) << 2))] = pv;
                }
            }
        }
        __syncthreads();
        #pragma unroll
        for (int it = 0; it < 8; ++it) {
            const int idx = (it << 8) + tid;
            const int row = idx >> 5, c4 = (idx & 31) << 2;
            f32x4 v = *(const f32x4*)&Lf[row * 128 + (c4 ^ ((row & 7) << 2))];
            float4 pv = {v[0], v[1], v[2], v[3]};
            *(float4*)(outp + (((size_t)((b << 8) + o0 + (h << 6) + row)) << 12) + s0 + c4) = pv;
        }
    }
}

// ---------- MFMA attention: one block per (b,c) ----------
__global__ __launch_bounds__(256) void attn_mfma_kernel(
    const _Float16* __restrict__ fx, const _Float16* __restrict__ gx,
    const _Float16* __restrict__ hx, _Float16* __restrict__ ob)
{
    __shared__ _Float16 L[23040];           // 46080 B
    const int FT = 0, GT = 4608, HM = 9216; // pitch-72 64-row panels
    const int FR = 13824, GR = 18432;       // raw staging
    const int PT = 13824;                   // P^T aliases FR

    const int t = threadIdx.x;
    const int wave = t >> 6, lane = t & 63, q = lane >> 4, li = lane & 15;
    const int bc = blockIdx.x;
    const _Float16* Fp = fx + (size_t)bc * SPA;
    const _Float16* Gp = gx + (size_t)bc * SPA;
    const _Float16* Hp = hx + (size_t)bc * SPA;
    _Float16* Op = ob + (size_t)bc * SPA;

    #pragma unroll
    for (int p = 0; p < 2; ++p) {
        int ci = t + (p << 8);
        int h = ci >> 3, w8 = (ci & 7) << 3;
        *(f16x8*)&L[FR + h * 72 + w8] = *(const f16x8*)(Fp + h * 64 + w8);
        *(f16x8*)&L[GR + h * 72 + w8] = *(const f16x8*)(Gp + h * 64 + w8);
        *(f16x8*)&L[HM + h * 72 + w8] = *(const f16x8*)(Hp + h * 64 + w8);
    }
    __syncthreads();

    // transpose F,G via MFMA x identity
    {
        const int src = (wave < 2) ? FR : GR;
        const int dst = (wave < 2) ? FT : GT;
        const int mtb = (wave & 1) << 1;
        f16x8 id0, id1;
        #pragma unroll
        for (int j = 0; j < 8; ++j) {
            id0[j] = (_Float16)(((q << 3) + j == li)      ? 1.0f : 0.0f);
            id1[j] = (_Float16)(((q << 3) + j == li + 16) ? 1.0f : 0.0f);
        }
        #pragma unroll
        for (int mi = 0; mi < 2; ++mi) {
            const int mt = mtb + mi;
            f16x8 a0 = *(const f16x8*)&L[src + (mt * 16 + li) * 72 + (q << 3)];
            f16x8 a1 = *(const f16x8*)&L[src + (mt * 16 + li) * 72 + 32 + (q << 3)];
            #pragma unroll
            for (int nt = 0; nt < 4; ++nt) {
                f32x4 d = {0.f, 0.f, 0.f, 0.f};
                d = __builtin_amdgcn_mfma_f32_16x16x32_f16(
                        (nt < 2) ? a0 : a1, (nt & 1) ? id1 : id0, d, 0, 0, 0);
                f16x4 e;
                e[0] = (_Float16)d[0]; e[1] = (_Float16)d[1];
                e[2] = (_Float16)d[2]; e[3] = (_Float16)d[3];
                *(f16x4*)&L[dst + (nt * 16 + li) * 72 + mt * 16 + (q << 2)] = e;
            }
        }
    }
    __syncthreads();

    // S-GEMM + register softmax
    {
        f16x8 a0 = *(const f16x8*)&L[FT + (wave * 16 + li) * 72 + (q << 3)];
        f16x8 a1 = *(const f16x8*)&L[FT + (wave * 16 + li) * 72 + 32 + (q << 3)];
        f32x4 s_[4];
        #pragma unroll
        for (int nt = 0; nt < 4; ++nt) {
            f16x8 b0 = *(const f16x8*)&L[GT + (nt * 16 + li) * 72 + (q << 3)];
            f16x8 b1 = *(const f16x8*)&L[GT + (nt * 16 + li) * 72 + 32 + (q << 3)];
            f32x4 acc = {0.f, 0.f, 0.f, 0.f};
            acc = __builtin_amdgcn_mfma_f32_16x16x32_f16(a0, b0, acc, 0, 0, 0);
            acc = __builtin_amdgcn_mfma_f32_16x16x32_f16(a1, b1, acc, 0, 0, 0);
            s_[nt] = acc;
        }
        float mx[4], sm[4];
        #pragma unroll
        for (int r = 0; r < 4; ++r) {
            float m0 = fmaxf(fmaxf(s_[0][r], s_[1][r]), fmaxf(s_[2][r], s_[3][r]));
            m0 = fmaxf(m0, __shfl_xor(m0, 1));
            m0 = fmaxf(m0, __shfl_xor(m0, 2));
            m0 = fmaxf(m0, __shfl_xor(m0, 4));
            m0 = fmaxf(m0, __shfl_xor(m0, 8));
            mx[r] = m0;
        }
        #pragma unroll
        for (int nt = 0; nt < 4; ++nt)
            #pragma unroll
            for (int r = 0; r < 4; ++r)
                s_[nt][r] = __expf(s_[nt][r] - mx[r]);
        #pragma unroll
        for (int r = 0; r < 4; ++r) {
            float s0 = (s_[0][r] + s_[1][r]) + (s_[2][r] + s_[3][r]);
            s0 += __shfl_xor(s0, 1);
            s0 += __shfl_xor(s0, 2);
            s0 += __shfl_xor(s0, 4);
            s0 += __shfl_xor(s0, 8);
            sm[r] = 1.f / s0;
        }
        #pragma unroll
        for (int nt = 0; nt < 4; ++nt) {
            const int v  = nt * 16 + li;
            const int sw = ((v >> 3) & 7) << 3;
            #pragma unroll
            for (int r = 0; r < 4; ++r) {
                const int w = wave * 16 + (q << 2) + r;
                L[PT + v * 72 + (w ^ sw)] = (_Float16)(s_[nt][r] * sm[r]);
            }
        }
    }
    __syncthreads();

    // O-GEMM
    {
        f16x8 a0 = *(const f16x8*)&L[HM + (wave * 16 + li) * 72 + (q << 3)];
        f16x8 a1 = *(const f16x8*)&L[HM + (wave * 16 + li) * 72 + 32 + (q << 3)];
        #pragma unroll
        for (int nt = 0; nt < 4; ++nt) {
            const int v  = nt * 16 + li;
            const int sw = ((v >> 3) & 7) << 3;
            f16x8 b0 = *(const f16x8*)&L[PT + v * 72 + ((q << 3) ^ sw)];
            f16x8 b1 = *(const f16x8*)&L[PT + v * 72 + ((32 + (q << 3)) ^ sw)];
            f32x4 acc = {0.f, 0.f, 0.f, 0.f};
            acc = __builtin_amdgcn_mfma_f32_16x16x32_f16(a0, b0, acc, 0, 0, 0);
            acc = __builtin_amdgcn_mfma_f32_16x16x32_f16(a1, b1, acc, 0, 0, 0);
            #pragma unroll
            for (int r = 0; r < 4; ++r)
                Op[(wave * 16 + (q << 2) + r) * 64 + v] = (_Float16)acc[r];
        }
    }
}

extern "C" void kernel_launch(void* const* d_in, const int* in_sizes, int n_in,
                              void* d_out, int out_size, void* d_ws, size_t ws_size,
                              hipStream_t stream)
{
    const float* x  = (const float*)d_in[0];
    const float* wf = (const float*)d_in[1];
    const float* bf = (const float*)d_in[2];
    const float* wg = (const float*)d_in[3];
    const float* bg = (const float*)d_in[4];
    const float* wh = (const float*)d_in[5];
    const float* bh = (const float*)d_in[6];
    const float* wv = (const float*)d_in[7];
    const float* bv = (const float*)d_in[8];

    char* base = (char*)d_ws;
    const size_t MB = 1ull << 20;
    _Float16* xT  = (_Float16*)base;               // [0,32)  MiB
    _Float16* fxb = (_Float16*)(base + 32 * MB);   // [32,64) (f), g [64,96), h [96,128)
    _Float16* ob  = (_Float16*)(base + 128 * MB);  // [128,160)
    _Float16* obT = (_Float16*)base;               // [0,32) — xT dead after convs
    _Float16* wc  = (_Float16*)(base + 160 * MB);  // 512 KB

    _Float16* gxb = fxb + PLANE;
    _Float16* hxb = gxb + PLANE;

    dim3 blk(256);
    xpose_kernel<<<4096, blk, 0, stream>>>(x, xT);
    wcvt_kernel<<<256, blk, 0, stream>>>(wf, wg, wh, wv, wc);

    gemm_fgh_kernel<<<4096, blk, 0, stream>>>(xT, wc, bf, bg, bh, fxb);

    attn_mfma_kernel<<<4096, blk, 0, stream>>>(fxb, gxb, hxb, ob);

    cpose_kernel<<<4096, blk, 0, stream>>>(ob, obT);

    gemm16_kernel<<<1024, blk, 0, stream>>>(obT, wc + 196608, bv, (float*)d_out);
}

// Round 10
// 243.409 us; speedup vs baseline: 1.0434x; 1.0073x over previous
//
#include <hip/hip_runtime.h>
#include <math.h>

#define CH  256
#define SPA 4096
#define BB  16
#define PLANE 16777216   // 16*256*4096 elements per tensor

typedef _Float16 f16x8 __attribute__((ext_vector_type(8)));
typedef _Float16 f16x4 __attribute__((ext_vector_type(4)));
typedef float    f32x4 __attribute__((ext_vector_type(4)));

__device__ __forceinline__ void gload16(const void* g, void* l) {
    __builtin_amdgcn_global_load_lds(
        (const __attribute__((address_space(1))) unsigned int*)g,
        (__attribute__((address_space(3))) unsigned int*)l, 16, 0, 0);
}

// ---------- x transpose + fp16 cvt: src[b][r][s] f32 -> dst[b][s][r] fp16 ----------
__global__ __launch_bounds__(256) void xpose_kernel(
    const float* __restrict__ src, _Float16* __restrict__ dst)
{
    __shared__ float T[64][65];
    const int t  = threadIdx.x;
    const int b  = blockIdx.x >> 8;
    const int st = (blockIdx.x >> 2) & 63;
    const int rt = blockIdx.x & 3;
    const int s0 = st << 6, r0 = rt << 6;

    #pragma unroll
    for (int p = 0; p < 4; ++p) {
        int k = (t >> 4) + (p << 4);
        float4 v = *(const float4*)(src + (((size_t)((b << 8) + r0 + k)) << 12)
                                        + s0 + ((t & 15) << 2));
        T[k][((t & 15) << 2) + 0] = v.x;
        T[k][((t & 15) << 2) + 1] = v.y;
        T[k][((t & 15) << 2) + 2] = v.z;
        T[k][((t & 15) << 2) + 3] = v.w;
    }
    __syncthreads();

    const int s  = t >> 2;
    const int kg = (t & 3) << 4;
    const size_t obase = (((size_t)((b << 12) + s0 + s)) << 8) + r0 + kg;

    f16x8 h0, h1;
    #pragma unroll
    for (int i = 0; i < 16; ++i) {
        _Float16 hv = (_Float16)T[kg + i][s];
        if (i < 8) h0[i] = hv; else h1[i - 8] = hv;
    }
    *(f16x8*)(dst + obase)     = h0;
    *(f16x8*)(dst + obase + 8) = h1;
}

// ---------- channel transpose fp16: src[b][c][s] -> dst[b][s][c] ----------
__global__ __launch_bounds__(256) void cpose_kernel(
    const _Float16* __restrict__ src, _Float16* __restrict__ dst)
{
    __shared__ _Float16 T[64][68];
    const int t  = threadIdx.x;
    const int b  = blockIdx.x >> 8;
    const int st = (blockIdx.x >> 2) & 63;
    const int ct = blockIdx.x & 3;
    const int s0 = st << 6, c0 = ct << 6;

    #pragma unroll
    for (int p = 0; p < 4; ++p) {
        int fi = (p << 8) + t;
        int r = fi >> 4, s4 = (fi & 15) << 2;
        f16x4 v = *(const f16x4*)(src + (((size_t)((b << 8) + c0 + r)) << 12) + s0 + s4);
        *(f16x4*)&T[r][s4] = v;
    }
    __syncthreads();

    const int s  = t >> 2;
    const int cg = (t & 3) << 4;
    f16x8 h0, h1;
    #pragma unroll
    for (int i = 0; i < 16; ++i) {
        _Float16 hv = T[cg + i][s];
        if (i < 8) h0[i] = hv; else h1[i - 8] = hv;
    }
    const size_t obase = (((size_t)((b << 12) + s0 + s)) << 8) + c0 + cg;
    *(f16x8*)(dst + obase)     = h0;
    *(f16x8*)(dst + obase + 8) = h1;
}

// ---------- weight cvt: 4 matrices [o][k] f32 -> fp16 ----------
__global__ __launch_bounds__(256) void wcvt_kernel(
    const float* __restrict__ w0, const float* __restrict__ w1,
    const float* __restrict__ w2, const float* __restrict__ w3,
    _Float16* __restrict__ dst)
{
    const int idx = blockIdx.x * 256 + threadIdx.x;
    dst[idx]             = (_Float16)w0[idx];
    dst[65536 + idx]     = (_Float16)w1[idx];
    dst[131072 + idx]    = (_Float16)w2[idx];
    dst[196608 + idx]    = (_Float16)w3[idx];
}

// ---------- fused f/g/h conv ----------
// v9 (kept): counted-vmcnt K-loop, lgkmcnt(0) WAR drain, 3-panel single-barrier
// coalesced epilogue, chunk-XOR swizzle, XCD remap.
__global__ __launch_bounds__(256, 4) void gemm_fgh_kernel(
    const _Float16* __restrict__ xT, const _Float16* __restrict__ wc,
    const float* __restrict__ bias0, const float* __restrict__ bias1,
    const float* __restrict__ bias2, _Float16* __restrict__ outp)
{
    __shared__ _Float16 S[2][8192];   // per buf: A 64x32 (2048) + 3x B 64x32 (2048)

    const int tid = threadIdx.x;
    const int w = tid >> 6, lane = tid & 63, q = lane >> 4, li = lane & 15;
    const int wx = w & 1, wy = w >> 1;      // wave owns 32s x 32o

    // XCD-aware remap (4096 blocks = 8 XCDs x 512)
    const int r_ = ((blockIdx.x & 7) << 9) + (blockIdx.x >> 3);
    const int ot    = r_ & 3;               // 4 o-tiles of 64
    const int stile = (r_ >> 2) & 63;       // 64 s-tiles of 64
    const int b     = r_ >> 8;              // 16 batches
    const int s0 = stile << 6, o0 = ot << 6;

    const float* biases[3] = {bias0, bias1, bias2};

    f32x4 acc[3][2][2];                     // [matrix][s-frag][o-frag]
    #pragma unroll
    for (int m = 0; m < 3; ++m)
        #pragma unroll
        for (int t2 = 0; t2 < 2; ++t2)
            #pragma unroll
            for (int u = 0; u < 2; ++u) acc[m][t2][u] = (f32x4){0.f, 0.f, 0.f, 0.f};

    const int rr = tid >> 2;                              // staged row 0..63
    const int cs = (((tid & 3) ^ ((rr >> 1) & 3)) << 3);  // pre-swizzled source k-chunk
    const int sw = (li >> 1) & 3;                         // read-side chunk XOR

    auto STAGE = [&](_Float16* sA, int kb) {              // 4 gload_lds per wave
        const size_t ga = (((size_t)((b << 12) + s0 + rr)) << 8) + kb + cs;
        gload16(xT + ga, sA + tid * 8);                   // A 64x32
        #pragma unroll
        for (int m = 0; m < 3; ++m) {
            const size_t gb = (((size_t)(o0 + rr)) << 8) + m * 65536 + kb + cs;
            gload16(wc + gb, sA + 2048 + m * 2048 + tid * 8);
        }
    };

    auto COMPUTE = [&](const _Float16* sA) {
        f16x8 a[2];
        #pragma unroll
        for (int t2 = 0; t2 < 2; ++t2)
            a[t2] = *(const f16x8*)(sA + (((wy << 5) + (t2 << 4) + li) * 32) + ((q ^ sw) << 3));
        #pragma unroll
        for (int m = 0; m < 3; ++m) {
            const _Float16* sB = sA + 2048 + m * 2048;
            f16x8 b0 = *(const f16x8*)(sB + (((wx << 5) + li) * 32) + ((q ^ sw) << 3));
            f16x8 b1 = *(const f16x8*)(sB + (((wx << 5) + 16 + li) * 32) + ((q ^ sw) << 3));
            #pragma unroll
            for (int t2 = 0; t2 < 2; ++t2) {
                acc[m][t2][0] = __builtin_amdgcn_mfma_f32_16x16x32_f16(a[t2], b0, acc[m][t2][0], 0, 0, 0);
                acc[m][t2][1] = __builtin_amdgcn_mfma_f32_16x16x32_f16(a[t2], b1, acc[m][t2][1], 0, 0, 0);
            }
        }
    };

    // prologue: stage tile 0 (no wait — first wait is in iter 0)
    STAGE(S[0], 0);

    #pragma unroll 1
    for (int ks = 0; ks < 7; ++ks) {
        STAGE(S[(ks + 1) & 1], (ks + 1) << 5);           // tile k+1 in flight
        asm volatile("s_waitcnt vmcnt(4)" ::: "memory"); // tile k's 4 loads done
        __builtin_amdgcn_s_barrier();                    // all waves' tile k landed
        COMPUTE(S[ks & 1]);
        asm volatile("s_waitcnt lgkmcnt(0)" ::: "memory"); // my ds_reads retired
        __builtin_amdgcn_s_barrier();                    // WAR: next STAGE overwrites
    }
    asm volatile("s_waitcnt vmcnt(0)" ::: "memory");     // drain tile 7
    __builtin_amdgcn_s_barrier();
    COMPUTE(S[1]);

    // ---- epilogue v9: 3 panels (m*4608 + o*72 + s), single barrier pair ----
    _Float16* Lr = &S[0][0];            // panels span 13824 halves of 16384
    __syncthreads();                    // all waves done reading S[1] (panels overlap)
    #pragma unroll
    for (int m = 0; m < 3; ++m) {
        #pragma unroll
        for (int u = 0; u < 2; ++u) {
            const int o = (wx << 5) + (u << 4) + li;
            const float bz = biases[m][o0 + o];
            #pragma unroll
            for (int t2 = 0; t2 < 2; ++t2) {
                const int s = (wy << 5) + (t2 << 4) + (q << 2);
                f32x4 v = acc[m][t2][u];
                f16x4 pv;
                pv[0] = (_Float16)(v[0] + bz); pv[1] = (_Float16)(v[1] + bz);
                pv[2] = (_Float16)(v[2] + bz); pv[3] = (_Float16)(v[3] + bz);
                *(f16x4*)&Lr[m * 4608 + o * 72 + s] = pv;
            }
        }
    }
    __syncthreads();                    // panels visible to all waves
    #pragma unroll
    for (int m = 0; m < 3; ++m) {       // stores stream back-to-back, no drains
        _Float16* ob = outp + (size_t)m * PLANE;
        #pragma unroll
        for (int it = 0; it < 2; ++it) {
            const int idx = (it << 8) + tid;
            const int row = idx >> 3, c8 = (idx & 7) << 3;
            f16x8 hv = *(const f16x8*)&Lr[m * 4608 + row * 72 + c8];
            *(f16x8*)(ob + (((size_t)((b << 8) + o0 + row)) << 12) + s0 + c8) = hv;
        }
    }
}

// ---------- final conv (single matrix, f32 out), 128s x 128o ----------
// v7: counted-vmcnt K-loop + lgkmcnt(0) WAR drain + coalesced f32 epilogue.
__global__ __launch_bounds__(256) void gemm16_kernel(
    const _Float16* __restrict__ xT, const _Float16* __restrict__ wp,
    const float* __restrict__ bias, float* __restrict__ outp)
{
    __shared__ _Float16 S[2][8192];    // per buf: A 128x32 + B 128x32

    const int tid = threadIdx.x;
    const int w = tid >> 6, lane = tid & 63, quad = lane >> 4, li = lane & 15;
    const int wx = w & 1, wy = w >> 1;

    // XCD-aware remap (1024 blocks = 8 XCDs x 128)
    const int r_ = ((blockIdx.x & 7) << 7) + (blockIdx.x >> 3);
    const int ot    = r_ & 1;
    const int stile = (r_ >> 1) & 31;
    const int b     = r_ >> 6;
    const int s0 = stile << 7, o0 = ot << 7;

    f32x4 acc[4][4];
    #pragma unroll
    for (int t2 = 0; t2 < 4; ++t2)
        #pragma unroll
        for (int u = 0; u < 4; ++u) acc[t2][u] = (f32x4){0.f, 0.f, 0.f, 0.f};

    const int rr = lane >> 2;
    const int cs = (((lane & 3) ^ ((rr >> 1) & 3)) << 3);  // pre-swizzled source chunk
    const int sw = (li >> 1) & 3;

    auto STAGE = [&](_Float16* sAB, int kb) {              // 4 gload_lds per wave
        #pragma unroll
        for (int j = 0; j < 32; j += 16) {
            const int r = (w << 5) + j + rr;
            const size_t ga = (((size_t)((b << 12) + s0 + r)) << 8) + kb + cs;
            const size_t gb = ((size_t)(o0 + r) << 8) + kb + cs;
            const int lo_ = ((w << 5) + j) * 32 + lane * 8;
            gload16(xT + ga, sAB + lo_);
            gload16(wp + gb, sAB + 4096 + lo_);
        }
    };

    auto COMPUTE = [&](const _Float16* sAB) {
        f16x8 a[4], bfr[4];
        #pragma unroll
        for (int t2 = 0; t2 < 4; ++t2) {
            a[t2]   = *(const f16x8*)(sAB + ((wy << 6) + (t2 << 4) + li) * 32 + ((quad ^ sw) << 3));
            bfr[t2] = *(const f16x8*)(sAB + 4096 + ((wx << 6) + (t2 << 4) + li) * 32 + ((quad ^ sw) << 3));
        }
        #pragma unroll
        for (int t2 = 0; t2 < 4; ++t2)
            #pragma unroll
            for (int u = 0; u < 4; ++u)
                acc[t2][u] = __builtin_amdgcn_mfma_f32_16x16x32_f16(a[t2], bfr[u], acc[t2][u], 0, 0, 0);
    };

    STAGE(S[0], 0);

    #pragma unroll 1
    for (int ks = 0; ks < 7; ++ks) {
        STAGE(S[(ks + 1) & 1], (ks + 1) << 5);
        asm volatile("s_waitcnt vmcnt(4)" ::: "memory");
        __builtin_amdgcn_s_barrier();
        COMPUTE(S[ks & 1]);
        asm volatile("s_waitcnt lgkmcnt(0)" ::: "memory");
        __builtin_amdgcn_s_barrier();
    }
    asm volatile("s_waitcnt vmcnt(0)" ::: "memory");
    __builtin_amdgcn_s_barrier();
    COMPUTE(S[1]);

    // ---- epilogue: per-o-half LDS repack, coalesced float4 streams ----
    float* Lf = (float*)&S[0][0];       // 64 rows x 128 f32 = 32 KB, XOR-swizzled
    #pragma unroll
    for (int h = 0; h < 2; ++h) {
        __syncthreads();
        if (wx == h) {
            #pragma unroll
            for (int u = 0; u < 4; ++u) {
                const int r = (u << 4) + li;
                const float bz = bias[o0 + (h << 6) + r];
                #pragma unroll
                for (int t2 = 0; t2 < 4; ++t2) {
                    const int s = (wy << 6) + (t2 << 4) + (quad << 2);
                    f32x4 v = acc[t2][u];
                    f32x4 pv = {v[0] + bz, v[1] + bz, v[2] + bz, v[3] + bz};
                    *(f32x4*)&Lf[r * 128 + (s ^ ((r & 7) << 2))] = pv;
                }
            }
        }
        __syncthreads();
        #pragma unroll
        for (int it = 0; it < 8; ++it) {
            const int idx = (it << 8) + tid;
            const int row = idx >> 5, c4 = (idx & 31) << 2;
            f32x4 v = *(const f32x4*)&Lf[row * 128 + (c4 ^ ((row & 7) << 2))];
            float4 pv = {v[0], v[1], v[2], v[3]};
            *(float4*)(outp + (((size_t)((b << 8) + o0 + (h << 6) + row)) << 12) + s0 + c4) = pv;
        }
    }
}

// ---------- MFMA attention: one block per (b,c) ----------
// v10: O-GEMM output repacked through LDS. Old: 16 scalar 2-B global stores
// per thread (lanes cover 4 rows x 32 B pieces = partial-line writes for all
// 32 MB). New: acc -> FT panel (dead after S-GEMM; 64x72, 144-B rows = 16-B
// aligned), one __syncthreads, then f16x8 streams: each wave stores 1 KB
// contiguous. Same fix that took gemm_fgh 62->49 us.
__global__ __launch_bounds__(256) void attn_mfma_kernel(
    const _Float16* __restrict__ fx, const _Float16* __restrict__ gx,
    const _Float16* __restrict__ hx, _Float16* __restrict__ ob)
{
    __shared__ _Float16 L[23040];           // 46080 B
    const int FT = 0, GT = 4608, HM = 9216; // pitch-72 64-row panels
    const int FR = 13824, GR = 18432;       // raw staging
    const int PT = 13824;                   // P^T aliases FR
    const int OT = 0;                       // output panel aliases FT (dead after S-GEMM)

    const int t = threadIdx.x;
    const int wave = t >> 6, lane = t & 63, q = lane >> 4, li = lane & 15;
    const int bc = blockIdx.x;
    const _Float16* Fp = fx + (size_t)bc * SPA;
    const _Float16* Gp = gx + (size_t)bc * SPA;
    const _Float16* Hp = hx + (size_t)bc * SPA;
    _Float16* Op = ob + (size_t)bc * SPA;

    #pragma unroll
    for (int p = 0; p < 2; ++p) {
        int ci = t + (p << 8);
        int h = ci >> 3, w8 = (ci & 7) << 3;
        *(f16x8*)&L[FR + h * 72 + w8] = *(const f16x8*)(Fp + h * 64 + w8);
        *(f16x8*)&L[GR + h * 72 + w8] = *(const f16x8*)(Gp + h * 64 + w8);
        *(f16x8*)&L[HM + h * 72 + w8] = *(const f16x8*)(Hp + h * 64 + w8);
    }
    __syncthreads();

    // transpose F,G via MFMA x identity
    {
        const int src = (wave < 2) ? FR : GR;
        const int dst = (wave < 2) ? FT : GT;
        const int mtb = (wave & 1) << 1;
        f16x8 id0, id1;
        #pragma unroll
        for (int j = 0; j < 8; ++j) {
            id0[j] = (_Float16)(((q << 3) + j == li)      ? 1.0f : 0.0f);
            id1[j] = (_Float16)(((q << 3) + j == li + 16) ? 1.0f : 0.0f);
        }
        #pragma unroll
        for (int mi = 0; mi < 2; ++mi) {
            const int mt = mtb + mi;
            f16x8 a0 = *(const f16x8*)&L[src + (mt * 16 + li) * 72 + (q << 3)];
            f16x8 a1 = *(const f16x8*)&L[src + (mt * 16 + li) * 72 + 32 + (q << 3)];
            #pragma unroll
            for (int nt = 0; nt < 4; ++nt) {
                f32x4 d = {0.f, 0.f, 0.f, 0.f};
                d = __builtin_amdgcn_mfma_f32_16x16x32_f16(
                        (nt < 2) ? a0 : a1, (nt & 1) ? id1 : id0, d, 0, 0, 0);
                f16x4 e;
                e[0] = (_Float16)d[0]; e[1] = (_Float16)d[1];
                e[2] = (_Float16)d[2]; e[3] = (_Float16)d[3];
                *(f16x4*)&L[dst + (nt * 16 + li) * 72 + mt * 16 + (q << 2)] = e;
            }
        }
    }
    __syncthreads();

    // S-GEMM + register softmax
    {
        f16x8 a0 = *(const f16x8*)&L[FT + (wave * 16 + li) * 72 + (q << 3)];
        f16x8 a1 = *(const f16x8*)&L[FT + (wave * 16 + li) * 72 + 32 + (q << 3)];
        f32x4 s_[4];
        #pragma unroll
        for (int nt = 0; nt < 4; ++nt) {
            f16x8 b0 = *(const f16x8*)&L[GT + (nt * 16 + li) * 72 + (q << 3)];
            f16x8 b1 = *(const f16x8*)&L[GT + (nt * 16 + li) * 72 + 32 + (q << 3)];
            f32x4 acc = {0.f, 0.f, 0.f, 0.f};
            acc = __builtin_amdgcn_mfma_f32_16x16x32_f16(a0, b0, acc, 0, 0, 0);
            acc = __builtin_amdgcn_mfma_f32_16x16x32_f16(a1, b1, acc, 0, 0, 0);
            s_[nt] = acc;
        }
        float mx[4], sm[4];
        #pragma unroll
        for (int r = 0; r < 4; ++r) {
            float m0 = fmaxf(fmaxf(s_[0][r], s_[1][r]), fmaxf(s_[2][r], s_[3][r]));
            m0 = fmaxf(m0, __shfl_xor(m0, 1));
            m0 = fmaxf(m0, __shfl_xor(m0, 2));
            m0 = fmaxf(m0, __shfl_xor(m0, 4));
            m0 = fmaxf(m0, __shfl_xor(m0, 8));
            mx[r] = m0;
        }
        #pragma unroll
        for (int nt = 0; nt < 4; ++nt)
            #pragma unroll
            for (int r = 0; r < 4; ++r)
                s_[nt][r] = __expf(s_[nt][r] - mx[r]);
        #pragma unroll
        for (int r = 0; r < 4; ++r) {
            float s0 = (s_[0][r] + s_[1][r]) + (s_[2][r] + s_[3][r]);
            s0 += __shfl_xor(s0, 1);
            s0 += __shfl_xor(s0, 2);
            s0 += __shfl_xor(s0, 4);
            s0 += __shfl_xor(s0, 8);
            sm[r] = 1.f / s0;
        }
        #pragma unroll
        for (int nt = 0; nt < 4; ++nt) {
            const int v  = nt * 16 + li;
            const int sw = ((v >> 3) & 7) << 3;
            #pragma unroll
            for (int r = 0; r < 4; ++r) {
                const int w = wave * 16 + (q << 2) + r;
                L[PT + v * 72 + (w ^ sw)] = (_Float16)(s_[nt][r] * sm[r]);
            }
        }
    }
    __syncthreads();

    // O-GEMM -> LDS panel (FT region, disjoint from HM/PT reads) -> coalesced store
    {
        f16x8 a0 = *(const f16x8*)&L[HM + (wave * 16 + li) * 72 + (q << 3)];
        f16x8 a1 = *(const f16x8*)&L[HM + (wave * 16 + li) * 72 + 32 + (q << 3)];
        #pragma unroll
        for (int nt = 0; nt < 4; ++nt) {
            const int v  = nt * 16 + li;
            const int sw = ((v >> 3) & 7) << 3;
            f16x8 b0 = *(const f16x8*)&L[PT + v * 72 + ((q << 3) ^ sw)];
            f16x8 b1 = *(const f16x8*)&L[PT + v * 72 + ((32 + (q << 3)) ^ sw)];
            f32x4 acc = {0.f, 0.f, 0.f, 0.f};
            acc = __builtin_amdgcn_mfma_f32_16x16x32_f16(a0, b0, acc, 0, 0, 0);
            acc = __builtin_amdgcn_mfma_f32_16x16x32_f16(a1, b1, acc, 0, 0, 0);
            #pragma unroll
            for (int r = 0; r < 4; ++r)
                L[OT + (wave * 16 + (q << 2) + r) * 72 + v] = (_Float16)acc[r];
        }
    }
    __syncthreads();                    // panel visible to all waves
    #pragma unroll
    for (int p = 0; p < 2; ++p) {       // stream: 1 KB contiguous per wave-store
        const int idx = (p << 8) + t;
        const int row = idx >> 3, c8 = (idx & 7) << 3;
        f16x8 hv = *(const f16x8*)&L[OT + row * 72 + c8];
        *(f16x8*)(Op + row * 64 + c8) = hv;
    }
}

extern "C" void kernel_launch(void* const* d_in, const int* in_sizes, int n_in,
                              void* d_out, int out_size, void* d_ws, size_t ws_size,
                              hipStream_t stream)
{
    const float* x  = (const float*)d_in[0];
    const float* wf = (const float*)d_in[1];
    const float* bf = (const float*)d_in[2];
    const float* wg = (const float*)d_in[3];
    const float* bg = (const float*)d_in[4];
    const float* wh = (const float*)d_in[5];
    const float* bh = (const float*)d_in[6];
    const float* wv = (const float*)d_in[7];
    const float* bv = (const float*)d_in[8];

    char* base = (char*)d_ws;
    const size_t MB = 1ull << 20;
    _Float16* xT  = (_Float16*)base;               // [0,32)  MiB
    _Float16* fxb = (_Float16*)(base + 32 * MB);   // [32,64) (f), g [64,96), h [96,128)
    _Float16* ob  = (_Float16*)(base + 128 * MB);  // [128,160)
    _Float16* obT = (_Float16*)base;               // [0,32) — xT dead after convs
    _Float16* wc  = (_Float16*)(base + 160 * MB);  // 512 KB

    _Float16* gxb = fxb + PLANE;
    _Float16* hxb = gxb + PLANE;

    dim3 blk(256);
    xpose_kernel<<<4096, blk, 0, stream>>>(x, xT);
    wcvt_kernel<<<256, blk, 0, stream>>>(wf, wg, wh, wv, wc);

    gemm_fgh_kernel<<<4096, blk, 0, stream>>>(xT, wc, bf, bg, bh, fxb);

    attn_mfma_kernel<<<4096, blk, 0, stream>>>(fxb, gxb, hxb, ob);

    cpose_kernel<<<4096, blk, 0, stream>>>(ob, obT);

    gemm16_kernel<<<1024, blk, 0, stream>>>(obT, wc + 196608, bv, (float*)d_out);
}